// Round 1
// baseline (5286.058 us; speedup 1.0000x reference)
//
#include <hip/hip_runtime.h>
#include <hip/hip_bf16.h>
#include <stdint.h>

// NeuralFSM: N nodes with one-hot state over S=8 states, E edges, 20 iterations.
// Key insight: state stays exactly one-hot -> simulate as uint8 FSM.
//   mask[dst] |= 1 << state[src]   (over all edges)
//   state[n]  = nextT[mask[n]*8 + state[n]];  mask[n] = 0
// where nextT[char*8+s] = argmax_t T[char][s][t]  (2048-byte table).
// Output: one-hot float32 [N,8] of final state. Exact (absmax 0).

#define NN 100000
#define EE 6400000
#define NCHARS 2048   // 256 chars * 8 states
#define ITERS 20

__global__ void setup_kernel(const float* __restrict__ s0,
                             const float* __restrict__ T,
                             uint8_t* __restrict__ state,
                             uint32_t* __restrict__ mask,
                             uint8_t* __restrict__ nextT) {
    int i = blockIdx.x * blockDim.x + threadIdx.x;
    if (i < NCHARS) {
        const float* row = T + i * 8;
        int t = 0;
        #pragma unroll
        for (int k = 1; k < 8; ++k) if (row[k] > 0.5f) t = k;
        nextT[i] = (uint8_t)t;
    }
    if (i < NN) {
        const float* row = s0 + i * 8;
        int s = 0;
        #pragma unroll
        for (int k = 1; k < 8; ++k) if (row[k] > 0.5f) s = k;
        state[i] = (uint8_t)s;
        mask[i] = 0u;
    }
}

__global__ void edge_kernel(const int* __restrict__ src,
                            const int* __restrict__ dst,
                            const uint8_t* __restrict__ state,
                            uint32_t* __restrict__ mask) {
    int i = blockIdx.x * blockDim.x + threadIdx.x;
    int stride = gridDim.x * blockDim.x;
    for (int e = i; e < EE; e += stride) {
        int s = src[e];
        int d = dst[e];
        atomicOr(&mask[d], 1u << state[s]);
    }
}

__global__ void update_kernel(uint8_t* __restrict__ state,
                              uint32_t* __restrict__ mask,
                              const uint8_t* __restrict__ nextT) {
    int i = blockIdx.x * blockDim.x + threadIdx.x;
    if (i < NN) {
        uint32_t m = mask[i];
        state[i] = nextT[(m << 3) + state[i]];
        mask[i] = 0u;
    }
}

__global__ void output_kernel(const uint8_t* __restrict__ state,
                              float* __restrict__ out) {
    int i = blockIdx.x * blockDim.x + threadIdx.x;
    if (i < NN) {
        int s = state[i];
        float4 lo = make_float4(0.f, 0.f, 0.f, 0.f);
        float4 hi = make_float4(0.f, 0.f, 0.f, 0.f);
        if (s == 0) lo.x = 1.f; else if (s == 1) lo.y = 1.f;
        else if (s == 2) lo.z = 1.f; else if (s == 3) lo.w = 1.f;
        else if (s == 4) hi.x = 1.f; else if (s == 5) hi.y = 1.f;
        else if (s == 6) hi.z = 1.f; else hi.w = 1.f;
        float4* o = (float4*)(out + (size_t)i * 8);
        o[0] = lo;
        o[1] = hi;
    }
}

extern "C" void kernel_launch(void* const* d_in, const int* in_sizes, int n_in,
                              void* d_out, int out_size, void* d_ws, size_t ws_size,
                              hipStream_t stream) {
    const float* s0        = (const float*)d_in[0];
    const int*   edge_idx  = (const int*)d_in[1];   // [2, E] flat: row0=src, row1=dst
    const float* T         = (const float*)d_in[2];
    float*       out       = (float*)d_out;

    const int* src = edge_idx;
    const int* dst = edge_idx + EE;

    // workspace layout
    uint8_t* ws = (uint8_t*)d_ws;
    uint32_t* mask  = (uint32_t*)ws;                 // 400000 B
    uint8_t*  state = ws + 400000;                   // 100000 B
    uint8_t*  nextT = ws + 500000;                   // 2048 B

    const int tb = 256;
    const int node_blocks = (NN + tb - 1) / tb;      // 391
    const int edge_blocks = 2048;

    setup_kernel<<<node_blocks, tb, 0, stream>>>(s0, T, state, mask, nextT);

    for (int it = 0; it < ITERS; ++it) {
        edge_kernel<<<edge_blocks, tb, 0, stream>>>(src, dst, state, mask);
        update_kernel<<<node_blocks, tb, 0, stream>>>(state, mask, nextT);
    }

    output_kernel<<<node_blocks, tb, 0, stream>>>(state, out);
}

// Round 2
// 1533.211 us; speedup vs baseline: 3.4477x; 3.4477x over previous
//
#include <hip/hip_runtime.h>
#include <hip/hip_bf16.h>
#include <stdint.h>

// NeuralFSM as integer FSM (exact). R2: static graph -> build CSR of incoming
// edges ONCE (2 atomic passes), then 20 iterations are pure gathers:
//   wave per node: m = OR over in-neighbors of (1 << state[src]);
//   state'[n] = nextT[m*8 + state[n]]   (ping-pong state buffers)
// This removes the 20x per-iteration memory-side atomic wall (199 MB
// WRITE_SIZE per edge_kernel dispatch in R1).

#define NN 100000
#define EE 6400000
#define NCHARS 2048
#define ITERS 20
#define NB_NODE 391      // ceil(100000/256)

// ---------- decode inputs + zero counts ----------
__global__ void decode_kernel(const float* __restrict__ s0,
                              const float* __restrict__ T,
                              uint8_t* __restrict__ state,
                              uint8_t* __restrict__ nextT,
                              uint32_t* __restrict__ counts) {
    int i = blockIdx.x * blockDim.x + threadIdx.x;
    if (i < NCHARS) {
        const float* row = T + i * 8;
        int t = 0;
        #pragma unroll
        for (int k = 1; k < 8; ++k) if (row[k] > 0.5f) t = k;
        nextT[i] = (uint8_t)t;
    }
    if (i < NN) {
        const float* row = s0 + i * 8;
        int s = 0;
        #pragma unroll
        for (int k = 1; k < 8; ++k) if (row[k] > 0.5f) s = k;
        state[i] = (uint8_t)s;
        counts[i] = 0u;
    }
}

// ---------- CSR build ----------
__global__ void hist_kernel(const int* __restrict__ dst, uint32_t* __restrict__ counts) {
    int i = blockIdx.x * blockDim.x + threadIdx.x;
    int stride = gridDim.x * blockDim.x;
    for (int e = i; e < EE; e += stride) atomicAdd(&counts[dst[e]], 1u);
}

__global__ void scan_blocksum_kernel(const uint32_t* __restrict__ counts,
                                     uint32_t* __restrict__ blocksum) {
    __shared__ uint32_t sdata[4];
    int t = threadIdx.x;
    int i = blockIdx.x * 256 + t;
    uint32_t v = (i < NN) ? counts[i] : 0u;
    #pragma unroll
    for (int off = 32; off; off >>= 1) v += __shfl_down(v, off);
    if ((t & 63) == 0) sdata[t >> 6] = v;
    __syncthreads();
    if (t == 0) blocksum[blockIdx.x] = sdata[0] + sdata[1] + sdata[2] + sdata[3];
}

__global__ void scan_offsets_kernel(const uint32_t* __restrict__ blocksum,
                                    uint32_t* __restrict__ blockoff, int nb) {
    __shared__ uint32_t lds[512];
    int t = threadIdx.x;
    uint32_t v = (t < nb) ? blocksum[t] : 0u;
    lds[t] = v;
    __syncthreads();
    for (int off = 1; off < 512; off <<= 1) {
        uint32_t x = (t >= off) ? lds[t - off] : 0u;
        __syncthreads();
        lds[t] += x;
        __syncthreads();
    }
    if (t < nb) blockoff[t] = lds[t] - v;   // exclusive
}

__global__ void scan_final_kernel(const uint32_t* __restrict__ counts,
                                  const uint32_t* __restrict__ blockoff,
                                  uint32_t* __restrict__ rowptr,
                                  uint32_t* __restrict__ cursor) {
    __shared__ uint32_t lds[256];
    int t = threadIdx.x;
    int i = blockIdx.x * 256 + t;
    uint32_t v = (i < NN) ? counts[i] : 0u;
    lds[t] = v;
    __syncthreads();
    for (int off = 1; off < 256; off <<= 1) {
        uint32_t x = (t >= off) ? lds[t - off] : 0u;
        __syncthreads();
        lds[t] += x;
        __syncthreads();
    }
    if (i < NN) {
        uint32_t r = blockoff[blockIdx.x] + lds[t] - v;
        rowptr[i] = r;
        cursor[i] = r;
    }
    if (i == 0) rowptr[NN] = EE;
}

__global__ void scatter_kernel(const int* __restrict__ src, const int* __restrict__ dst,
                               uint32_t* __restrict__ cursor, uint32_t* __restrict__ csr_src) {
    int i = blockIdx.x * blockDim.x + threadIdx.x;
    int stride = gridDim.x * blockDim.x;
    for (int e = i; e < EE; e += stride) {
        int d = dst[e];
        uint32_t pos = atomicAdd(&cursor[d], 1u);
        csr_src[pos] = (uint32_t)src[e];
    }
}

// ---------- per-iteration gather (wave per node, no atomics) ----------
__global__ void gather_kernel(const uint32_t* __restrict__ rowptr,
                              const uint32_t* __restrict__ csr_src,
                              const uint8_t* __restrict__ state_cur,
                              uint8_t* __restrict__ state_next,
                              const uint8_t* __restrict__ nextT) {
    int n = blockIdx.x * (blockDim.x >> 6) + (threadIdx.x >> 6);
    if (n >= NN) return;
    int lane = threadIdx.x & 63;
    uint32_t start = rowptr[n], end = rowptr[n + 1];
    uint32_t m = 0;
    for (uint32_t e = start + lane; e < end; e += 64)
        m |= 1u << state_cur[csr_src[e]];
    #pragma unroll
    for (int off = 32; off; off >>= 1) m |= __shfl_xor(m, off);
    if (lane == 0) state_next[n] = nextT[(m << 3) + state_cur[n]];
}

__global__ void output_kernel(const uint8_t* __restrict__ state, float* __restrict__ out) {
    int i = blockIdx.x * blockDim.x + threadIdx.x;
    if (i < NN) {
        int s = state[i];
        float4 lo = make_float4(s == 0 ? 1.f : 0.f, s == 1 ? 1.f : 0.f,
                                s == 2 ? 1.f : 0.f, s == 3 ? 1.f : 0.f);
        float4 hi = make_float4(s == 4 ? 1.f : 0.f, s == 5 ? 1.f : 0.f,
                                s == 6 ? 1.f : 0.f, s == 7 ? 1.f : 0.f);
        float4* o = (float4*)(out + (size_t)i * 8);
        o[0] = lo;
        o[1] = hi;
    }
}

// ---------- R1 fallback kernels (used only if ws too small for CSR) ----------
__global__ void fb_edge_kernel(const int* __restrict__ src, const int* __restrict__ dst,
                               const uint8_t* __restrict__ state, uint32_t* __restrict__ mask) {
    int i = blockIdx.x * blockDim.x + threadIdx.x;
    int stride = gridDim.x * blockDim.x;
    for (int e = i; e < EE; e += stride) atomicOr(&mask[dst[e]], 1u << state[src[e]]);
}
__global__ void fb_update_kernel(uint8_t* __restrict__ state, uint32_t* __restrict__ mask,
                                 const uint8_t* __restrict__ nextT) {
    int i = blockIdx.x * blockDim.x + threadIdx.x;
    if (i < NN) {
        uint32_t m = mask[i];
        state[i] = nextT[(m << 3) + state[i]];
        mask[i] = 0u;
    }
}

extern "C" void kernel_launch(void* const* d_in, const int* in_sizes, int n_in,
                              void* d_out, int out_size, void* d_ws, size_t ws_size,
                              hipStream_t stream) {
    const float* s0  = (const float*)d_in[0];
    const int*   ei  = (const int*)d_in[1];   // [2,E]: row0=src, row1=dst
    const float* T   = (const float*)d_in[2];
    float*       out = (float*)d_out;
    const int* src = ei;
    const int* dst = ei + EE;

    uint8_t* base = (uint8_t*)d_ws;
    size_t off = 0;
    auto alloc = [&](size_t sz) -> void* {
        void* p = base + off;
        off += (sz + 255) & ~(size_t)255;
        return p;
    };
    uint32_t* rowptr   = (uint32_t*)alloc(sizeof(uint32_t) * (NN + 1));
    uint32_t* cursor   = (uint32_t*)alloc(sizeof(uint32_t) * NN);
    uint32_t* counts   = (uint32_t*)alloc(sizeof(uint32_t) * NN);
    uint32_t* blocksum = (uint32_t*)alloc(sizeof(uint32_t) * 512);
    uint32_t* blockoff = (uint32_t*)alloc(sizeof(uint32_t) * 512);
    uint8_t*  nextT    = (uint8_t*)alloc(NCHARS);
    uint8_t*  stateA   = (uint8_t*)alloc(NN);
    uint8_t*  stateB   = (uint8_t*)alloc(NN);
    uint32_t* csr_src  = (uint32_t*)alloc(sizeof(uint32_t) * EE);
    bool have_ws = (off <= ws_size);

    const int tb = 256;
    if (have_ws) {
        decode_kernel<<<NB_NODE, tb, 0, stream>>>(s0, T, stateA, nextT, counts);
        hist_kernel<<<8192, tb, 0, stream>>>(dst, counts);
        scan_blocksum_kernel<<<NB_NODE, tb, 0, stream>>>(counts, blocksum);
        scan_offsets_kernel<<<1, 512, 0, stream>>>(blocksum, blockoff, NB_NODE);
        scan_final_kernel<<<NB_NODE, tb, 0, stream>>>(counts, blockoff, rowptr, cursor);
        scatter_kernel<<<8192, tb, 0, stream>>>(src, dst, cursor, csr_src);

        const int gblocks = (NN + 3) / 4;   // 4 waves (nodes) per 256-thread block
        uint8_t* cur = stateA;
        uint8_t* nxt = stateB;
        for (int it = 0; it < ITERS; ++it) {
            gather_kernel<<<gblocks, tb, 0, stream>>>(rowptr, csr_src, cur, nxt, nextT);
            uint8_t* tmp = cur; cur = nxt; nxt = tmp;
        }
        output_kernel<<<NB_NODE, tb, 0, stream>>>(cur, out);
    } else {
        // R1 fallback: mask-based atomics (needs < 1 MB of ws)
        uint32_t* mask = rowptr;   // reuse
        decode_kernel<<<NB_NODE, tb, 0, stream>>>(s0, T, stateA, nextT, mask);
        for (int it = 0; it < ITERS; ++it) {
            fb_edge_kernel<<<2048, tb, 0, stream>>>(src, dst, stateA, mask);
            fb_update_kernel<<<NB_NODE, tb, 0, stream>>>(stateA, mask, nextT);
        }
        output_kernel<<<NB_NODE, tb, 0, stream>>>(stateA, out);
    }
}

// Round 3
// 848.495 us; speedup vs baseline: 6.2299x; 1.8070x over previous
//
#include <hip/hip_runtime.h>
#include <hip/hip_bf16.h>
#include <stdint.h>

// NeuralFSM as integer FSM (exact). R3: CSR build WITHOUT per-edge global
// atomics (R2's scatter burned 387MB TCC writes for 25.6MB payload).
// Two-level LDS bucket sort:
//   P1: per-8192-edge chunk LDS histogram over 500 dst-buckets (200 nodes ea)
//   P2a: per-bucket exclusive scan over chunks (in-place on hist)
//   P2b: scan bucket totals -> bucket_base
//   P3: re-read chunks, LDS cursors, write packed (dst_local<<17|src) to
//       bucket regions (contiguous per-(chunk,bucket) segments, no atomics)
//   P4: block per bucket: stage ~12.8K edges in LDS, local hist+scan of 200
//       nodes -> rowptr, scatter src back IN-PLACE (region L2-local)
// Then 20 gather iterations (wave per node, shfl-OR), as R2.

#define NN 100000
#define EE 6400000
#define NCHARS 2048
#define ITERS 20
#define NB_NODE 391       // ceil(NN/256)

#define NBKT 500          // buckets
#define NPB 200           // nodes per bucket (NBKT*NPB == NN)
#define CEDGE 8192        // edges per chunk
#define NCHUNK 782        // ceil(EE/CEDGE)
#define CAP 14336         // LDS edge capacity per bucket (mean 12800, +13 sigma)

// ---------- decode inputs ----------
__global__ void decode_kernel(const float* __restrict__ s0,
                              const float* __restrict__ T,
                              uint8_t* __restrict__ state,
                              uint8_t* __restrict__ nextT) {
    int i = blockIdx.x * blockDim.x + threadIdx.x;
    if (i < NCHARS) {
        const float* row = T + i * 8;
        int t = 0;
        #pragma unroll
        for (int k = 1; k < 8; ++k) if (row[k] > 0.5f) t = k;
        nextT[i] = (uint8_t)t;
    }
    if (i < NN) {
        const float* row = s0 + i * 8;
        int s = 0;
        #pragma unroll
        for (int k = 1; k < 8; ++k) if (row[k] > 0.5f) s = k;
        state[i] = (uint8_t)s;
    }
}

// ---------- P1: per-chunk bucket histogram ----------
__global__ void p1_hist(const int* __restrict__ dst, uint32_t* __restrict__ hist) {
    __shared__ uint32_t cnt[NBKT];
    int t = threadIdx.x;
    int c = blockIdx.x;
    for (int i = t; i < NBKT; i += 256) cnt[i] = 0;
    __syncthreads();
    int estart = c * CEDGE;
    int eend = min(EE, estart + CEDGE);
    for (int e = estart + t; e < eend; e += 256)
        atomicAdd(&cnt[dst[e] / NPB], 1u);
    __syncthreads();
    for (int i = t; i < NBKT; i += 256) hist[(size_t)c * NBKT + i] = cnt[i];
}

// ---------- P2a: per-bucket exclusive scan over chunks (in-place) ----------
__global__ void p2a_scan(uint32_t* __restrict__ hist, uint32_t* __restrict__ total) {
    __shared__ uint32_t lds[256];
    int t = threadIdx.x;
    int b = blockIdx.x;
    uint32_t carry = 0;
    for (int c0 = 0; c0 < NCHUNK; c0 += 256) {
        int c = c0 + t;
        uint32_t v = (c < NCHUNK) ? hist[(size_t)c * NBKT + b] : 0u;
        lds[t] = v;
        __syncthreads();
        for (int off = 1; off < 256; off <<= 1) {
            uint32_t x = (t >= off) ? lds[t - off] : 0u;
            __syncthreads();
            lds[t] += x;
            __syncthreads();
        }
        uint32_t incl = lds[t];
        if (c < NCHUNK) hist[(size_t)c * NBKT + b] = incl - v + carry;
        uint32_t tot = lds[255];
        __syncthreads();
        carry += tot;
    }
    if (t == 0) total[b] = carry;
}

// ---------- P2b: scan bucket totals ----------
__global__ void p2b_scan(const uint32_t* __restrict__ total,
                         uint32_t* __restrict__ bucket_base,
                         uint32_t* __restrict__ rowptr) {
    __shared__ uint32_t lds[512];
    int t = threadIdx.x;
    uint32_t v = (t < NBKT) ? total[t] : 0u;
    lds[t] = v;
    __syncthreads();
    for (int off = 1; off < 512; off <<= 1) {
        uint32_t x = (t >= off) ? lds[t - off] : 0u;
        __syncthreads();
        lds[t] += x;
        __syncthreads();
    }
    uint32_t incl = lds[t];
    if (t < NBKT) bucket_base[t] = incl - v;
    if (t == 511) bucket_base[NBKT] = lds[511];   // == EE
    if (t == 0) rowptr[NN] = EE;
}

// ---------- P3: partition edges into buckets (packed), no global atomics ----------
__global__ void p3_partition(const int* __restrict__ src, const int* __restrict__ dst,
                             const uint32_t* __restrict__ hist,
                             const uint32_t* __restrict__ bucket_base,
                             uint32_t* __restrict__ csr) {
    __shared__ uint32_t cur[NBKT];
    int t = threadIdx.x;
    int c = blockIdx.x;
    for (int i = t; i < NBKT; i += 256)
        cur[i] = bucket_base[i] + hist[(size_t)c * NBKT + i];
    __syncthreads();
    int estart = c * CEDGE;
    int eend = min(EE, estart + CEDGE);
    for (int e = estart + t; e < eend; e += 256) {
        int d = dst[e];
        int s = src[e];
        int b = d / NPB;
        uint32_t dl = (uint32_t)(d - b * NPB);
        uint32_t pos = atomicAdd(&cur[b], 1u);
        csr[pos] = (dl << 17) | (uint32_t)s;
    }
}

// ---------- P4: per-bucket LDS sort -> rowptr + in-place src CSR ----------
__global__ void __launch_bounds__(512) p4_sort(uint32_t* __restrict__ csr,
                                               const uint32_t* __restrict__ bucket_base,
                                               uint32_t* __restrict__ rowptr) {
    __shared__ uint32_t eLDS[CAP];
    __shared__ uint32_t cnt[NPB];
    __shared__ uint32_t scanbuf[512];
    int t = threadIdx.x;
    int b = blockIdx.x;
    uint32_t base = bucket_base[b];
    uint32_t end  = bucket_base[b + 1];
    int n = (int)(end - base);           // <= CAP (mean 12800, sigma 113)
    for (int i = t; i < n; i += 512) eLDS[i] = csr[base + i];
    for (int i = t; i < NPB; i += 512) cnt[i] = 0;
    __syncthreads();
    for (int i = t; i < n; i += 512) atomicAdd(&cnt[eLDS[i] >> 17], 1u);
    __syncthreads();
    uint32_t v = (t < NPB) ? cnt[t] : 0u;
    scanbuf[t] = v;
    __syncthreads();
    for (int off = 1; off < 512; off <<= 1) {
        uint32_t x = (t >= off) ? scanbuf[t - off] : 0u;
        __syncthreads();
        scanbuf[t] += x;
        __syncthreads();
    }
    if (t < NPB) {
        uint32_t excl = scanbuf[t] - v;
        rowptr[b * NPB + t] = base + excl;
        cnt[t] = base + excl;            // reuse as global cursor
    }
    __syncthreads();
    for (int i = t; i < n; i += 512) {
        uint32_t e = eLDS[i];
        uint32_t pos = atomicAdd(&cnt[e >> 17], 1u);
        csr[pos] = e & 0x1FFFFu;         // src only; in-place safe (fully staged)
    }
}

// ---------- per-iteration gather (wave per node, no atomics) ----------
__global__ void gather_kernel(const uint32_t* __restrict__ rowptr,
                              const uint32_t* __restrict__ csr_src,
                              const uint8_t* __restrict__ state_cur,
                              uint8_t* __restrict__ state_next,
                              const uint8_t* __restrict__ nextT) {
    int n = blockIdx.x * (blockDim.x >> 6) + (threadIdx.x >> 6);
    if (n >= NN) return;
    int lane = threadIdx.x & 63;
    uint32_t start = rowptr[n], end = rowptr[n + 1];
    uint32_t m = 0;
    for (uint32_t e = start + lane; e < end; e += 64)
        m |= 1u << state_cur[csr_src[e]];
    #pragma unroll
    for (int off = 32; off; off >>= 1) m |= __shfl_xor(m, off);
    if (lane == 0) state_next[n] = nextT[(m << 3) + state_cur[n]];
}

__global__ void output_kernel(const uint8_t* __restrict__ state, float* __restrict__ out) {
    int i = blockIdx.x * blockDim.x + threadIdx.x;
    if (i < NN) {
        int s = state[i];
        float4 lo = make_float4(s == 0 ? 1.f : 0.f, s == 1 ? 1.f : 0.f,
                                s == 2 ? 1.f : 0.f, s == 3 ? 1.f : 0.f);
        float4 hi = make_float4(s == 4 ? 1.f : 0.f, s == 5 ? 1.f : 0.f,
                                s == 6 ? 1.f : 0.f, s == 7 ? 1.f : 0.f);
        float4* o = (float4*)(out + (size_t)i * 8);
        o[0] = lo;
        o[1] = hi;
    }
}

// ---------- fallback (tiny ws): R1 mask/atomicOr path ----------
__global__ void fb_init(uint32_t* __restrict__ mask) {
    int i = blockIdx.x * blockDim.x + threadIdx.x;
    if (i < NN) mask[i] = 0u;
}
__global__ void fb_edge(const int* __restrict__ src, const int* __restrict__ dst,
                        const uint8_t* __restrict__ state, uint32_t* __restrict__ mask) {
    int i = blockIdx.x * blockDim.x + threadIdx.x;
    int stride = gridDim.x * blockDim.x;
    for (int e = i; e < EE; e += stride) atomicOr(&mask[dst[e]], 1u << state[src[e]]);
}
__global__ void fb_update(uint8_t* __restrict__ state, uint32_t* __restrict__ mask,
                          const uint8_t* __restrict__ nextT) {
    int i = blockIdx.x * blockDim.x + threadIdx.x;
    if (i < NN) {
        uint32_t m = mask[i];
        state[i] = nextT[(m << 3) + state[i]];
        mask[i] = 0u;
    }
}

extern "C" void kernel_launch(void* const* d_in, const int* in_sizes, int n_in,
                              void* d_out, int out_size, void* d_ws, size_t ws_size,
                              hipStream_t stream) {
    const float* s0  = (const float*)d_in[0];
    const int*   ei  = (const int*)d_in[1];   // [2,E]: row0=src, row1=dst
    const float* T   = (const float*)d_in[2];
    float*       out = (float*)d_out;
    const int* src = ei;
    const int* dst = ei + EE;

    uint8_t* basep = (uint8_t*)d_ws;
    size_t off = 0;
    auto alloc = [&](size_t sz) -> void* {
        void* p = basep + off;
        off += (sz + 255) & ~(size_t)255;
        return p;
    };
    uint32_t* csr         = (uint32_t*)alloc(sizeof(uint32_t) * EE);
    uint32_t* hist        = (uint32_t*)alloc(sizeof(uint32_t) * (size_t)NCHUNK * NBKT);
    uint32_t* total       = (uint32_t*)alloc(sizeof(uint32_t) * NBKT);
    uint32_t* bucket_base = (uint32_t*)alloc(sizeof(uint32_t) * (NBKT + 1));
    uint32_t* rowptr      = (uint32_t*)alloc(sizeof(uint32_t) * (NN + 1));
    uint8_t*  nextT       = (uint8_t*)alloc(NCHARS);
    uint8_t*  stateA      = (uint8_t*)alloc(NN);
    uint8_t*  stateB      = (uint8_t*)alloc(NN);
    bool have_ws = (off <= ws_size);

    const int tb = 256;
    if (have_ws) {
        decode_kernel<<<NB_NODE, tb, 0, stream>>>(s0, T, stateA, nextT);
        p1_hist<<<NCHUNK, tb, 0, stream>>>(dst, hist);
        p2a_scan<<<NBKT, tb, 0, stream>>>(hist, total);
        p2b_scan<<<1, 512, 0, stream>>>(total, bucket_base, rowptr);
        p3_partition<<<NCHUNK, tb, 0, stream>>>(src, dst, hist, bucket_base, csr);
        p4_sort<<<NBKT, 512, 0, stream>>>(csr, bucket_base, rowptr);

        const int gblocks = (NN + 3) / 4;
        uint8_t* cur = stateA;
        uint8_t* nxt = stateB;
        for (int it = 0; it < ITERS; ++it) {
            gather_kernel<<<gblocks, tb, 0, stream>>>(rowptr, csr, cur, nxt, nextT);
            uint8_t* tmp = cur; cur = nxt; nxt = tmp;
        }
        output_kernel<<<NB_NODE, tb, 0, stream>>>(cur, out);
    } else {
        uint32_t* mask = (uint32_t*)d_ws;           // < 1 MB path
        uint8_t*  nT   = (uint8_t*)d_ws + 400128;
        uint8_t*  st   = (uint8_t*)d_ws + 402432;
        decode_kernel<<<NB_NODE, tb, 0, stream>>>(s0, T, st, nT);
        fb_init<<<NB_NODE, tb, 0, stream>>>(mask);
        for (int it = 0; it < ITERS; ++it) {
            fb_edge<<<2048, tb, 0, stream>>>(src, dst, st, mask);
            fb_update<<<NB_NODE, tb, 0, stream>>>(st, mask, nT);
        }
        output_kernel<<<NB_NODE, tb, 0, stream>>>(st, out);
    }
}

// Round 4
// 502.758 us; speedup vs baseline: 10.5141x; 1.6877x over previous
//
#include <hip/hip_runtime.h>
#include <hip/hip_bf16.h>
#include <stdint.h>

// NeuralFSM as integer FSM (exact). R4:
//  - P3 uses 25600-edge chunks: per-(chunk,bucket) segments ~51 edges (204B)
//    -> kills R3's 6x write amplification (148MB -> ~45MB).
//  - Iterations no longer need per-node CSR: edges stay bucket-partitioned,
//    packed (src<<8)|dst_local, optionally bin-sorted by src>>8 for state-read
//    locality. Iteration kernel: block per bucket, LDS mask[200] accumulated
//    via LDS atomicOr (order-independent), then 200 table lookups.
//  - R3's gather did 64 scattered byte-gathers per wave instr; bin-sorting
//    confines a wave's state reads to ~2 x 256B windows (~6x fewer L2 reqs).

#define NN 100000
#define EE 6400000
#define NCHARS 2048
#define ITERS 20
#define NB_NODE 391       // ceil(NN/256)

#define NBKT 500          // dst buckets
#define NPB 200           // nodes per bucket (NBKT*NPB == NN)
#define CEDGE 25600       // edges per chunk
#define NCHUNK 250        // CEDGE*NCHUNK == EE exactly
#define CAP 14336         // per-bucket LDS capacity (mean 12800, +13 sigma)

// ---------- decode inputs ----------
__global__ void decode_kernel(const float* __restrict__ s0,
                              const float* __restrict__ T,
                              uint8_t* __restrict__ state,
                              uint8_t* __restrict__ nextT) {
    int i = blockIdx.x * blockDim.x + threadIdx.x;
    if (i < NCHARS) {
        const float* row = T + i * 8;
        int t = 0;
        #pragma unroll
        for (int k = 1; k < 8; ++k) if (row[k] > 0.5f) t = k;
        nextT[i] = (uint8_t)t;
    }
    if (i < NN) {
        const float* row = s0 + i * 8;
        int s = 0;
        #pragma unroll
        for (int k = 1; k < 8; ++k) if (row[k] > 0.5f) s = k;
        state[i] = (uint8_t)s;
    }
}

// ---------- P1: per-chunk bucket histogram ----------
__global__ void p1_hist(const int* __restrict__ dst, uint32_t* __restrict__ hist) {
    __shared__ uint32_t cnt[NBKT];
    int t = threadIdx.x;
    int c = blockIdx.x;
    for (int i = t; i < NBKT; i += 256) cnt[i] = 0;
    __syncthreads();
    int estart = c * CEDGE;
    for (int e = estart + t; e < estart + CEDGE; e += 256)
        atomicAdd(&cnt[dst[e] / NPB], 1u);
    __syncthreads();
    for (int i = t; i < NBKT; i += 256) hist[(size_t)c * NBKT + i] = cnt[i];
}

// ---------- P2a: per-bucket exclusive scan over chunks (NCHUNK<=256) ----------
__global__ void p2a_scan(uint32_t* __restrict__ hist, uint32_t* __restrict__ total) {
    __shared__ uint32_t lds[256];
    int t = threadIdx.x;
    int b = blockIdx.x;
    uint32_t v = (t < NCHUNK) ? hist[(size_t)t * NBKT + b] : 0u;
    lds[t] = v;
    __syncthreads();
    for (int off = 1; off < 256; off <<= 1) {
        uint32_t x = (t >= off) ? lds[t - off] : 0u;
        __syncthreads();
        lds[t] += x;
        __syncthreads();
    }
    if (t < NCHUNK) hist[(size_t)t * NBKT + b] = lds[t] - v;   // exclusive
    if (t == 0) total[b] = lds[255];
}

// ---------- P2b: scan bucket totals (NBKT<=512) ----------
__global__ void p2b_scan(const uint32_t* __restrict__ total,
                         uint32_t* __restrict__ bucket_base) {
    __shared__ uint32_t lds[512];
    int t = threadIdx.x;
    uint32_t v = (t < NBKT) ? total[t] : 0u;
    lds[t] = v;
    __syncthreads();
    for (int off = 1; off < 512; off <<= 1) {
        uint32_t x = (t >= off) ? lds[t - off] : 0u;
        __syncthreads();
        lds[t] += x;
        __syncthreads();
    }
    if (t < NBKT) bucket_base[t] = lds[t] - v;
    if (t == 511) bucket_base[NBKT] = lds[511];   // == EE
}

// ---------- P3: partition edges into buckets, packed (src<<8)|dst_local ----------
__global__ void p3_partition(const int* __restrict__ src, const int* __restrict__ dst,
                             const uint32_t* __restrict__ hist,
                             const uint32_t* __restrict__ bucket_base,
                             uint32_t* __restrict__ csr) {
    __shared__ uint32_t cur[NBKT];
    int t = threadIdx.x;
    int c = blockIdx.x;
    for (int i = t; i < NBKT; i += 256)
        cur[i] = bucket_base[i] + hist[(size_t)c * NBKT + i];
    __syncthreads();
    int estart = c * CEDGE;
    for (int e = estart + t; e < estart + CEDGE; e += 256) {
        int d = dst[e];
        int s = src[e];
        int b = d / NPB;
        uint32_t dl = (uint32_t)(d - b * NPB);        // < 200, fits 8 bits
        uint32_t pos = atomicAdd(&cur[b], 1u);
        csr[pos] = ((uint32_t)s << 8) | dl;           // src 17b | dl 8b
    }
}

// ---------- P4: per-bucket bin-sort by src>>8 (locality only; optional) ----------
__global__ void __launch_bounds__(512) p4_bin(uint32_t* __restrict__ csr,
                                              const uint32_t* __restrict__ bucket_base) {
    __shared__ uint32_t eLDS[CAP];
    __shared__ uint32_t hist[512];
    int t = threadIdx.x;
    int b = blockIdx.x;
    uint32_t base = bucket_base[b];
    int n = (int)(bucket_base[b + 1] - base);
    if (n > CAP) return;                 // rare: leave unsorted (still correct)
    for (int i = t; i < n; i += 512) eLDS[i] = csr[base + i];
    hist[t] = 0;
    __syncthreads();
    for (int i = t; i < n; i += 512) atomicAdd(&hist[eLDS[i] >> 16], 1u);  // src>>8, 9 bits
    __syncthreads();
    uint32_t v = hist[t];
    __syncthreads();
    // inclusive scan over 512 (in place)
    for (int off = 1; off < 512; off <<= 1) {
        uint32_t x = (t >= off) ? hist[t - off] : 0u;
        __syncthreads();
        hist[t] += x;
        __syncthreads();
    }
    uint32_t excl = hist[t] - v;
    __syncthreads();
    hist[t] = excl;                      // becomes scatter cursor
    __syncthreads();
    for (int i = t; i < n; i += 512) {
        uint32_t e = eLDS[i];
        uint32_t pos = atomicAdd(&hist[e >> 16], 1u);
        csr[base + pos] = e;
    }
}

// ---------- per-iteration: block per bucket, LDS mask accumulate ----------
__global__ void __launch_bounds__(512) iter_kernel(const uint32_t* __restrict__ csr,
                                                   const uint32_t* __restrict__ bucket_base,
                                                   const uint8_t* __restrict__ state_cur,
                                                   uint8_t* __restrict__ state_next,
                                                   const uint8_t* __restrict__ nextT) {
    __shared__ uint32_t mask[NPB];
    int t = threadIdx.x;
    int b = blockIdx.x;
    if (t < NPB) mask[t] = 0;
    __syncthreads();
    uint32_t base = bucket_base[b];
    uint32_t end  = bucket_base[b + 1];
    for (uint32_t e = base + t; e < end; e += 512) {
        uint32_t p = csr[e];
        uint32_t s = state_cur[p >> 8];
        atomicOr(&mask[p & 0xFFu], 1u << s);
    }
    __syncthreads();
    if (t < NPB) {
        int node = b * NPB + t;
        state_next[node] = nextT[(mask[t] << 3) + state_cur[node]];
    }
}

__global__ void output_kernel(const uint8_t* __restrict__ state, float* __restrict__ out) {
    int i = blockIdx.x * blockDim.x + threadIdx.x;
    if (i < NN) {
        int s = state[i];
        float4 lo = make_float4(s == 0 ? 1.f : 0.f, s == 1 ? 1.f : 0.f,
                                s == 2 ? 1.f : 0.f, s == 3 ? 1.f : 0.f);
        float4 hi = make_float4(s == 4 ? 1.f : 0.f, s == 5 ? 1.f : 0.f,
                                s == 6 ? 1.f : 0.f, s == 7 ? 1.f : 0.f);
        float4* o = (float4*)(out + (size_t)i * 8);
        o[0] = lo;
        o[1] = hi;
    }
}

// ---------- fallback (tiny ws): R1 mask/atomicOr path ----------
__global__ void fb_init(uint32_t* __restrict__ mask) {
    int i = blockIdx.x * blockDim.x + threadIdx.x;
    if (i < NN) mask[i] = 0u;
}
__global__ void fb_edge(const int* __restrict__ src, const int* __restrict__ dst,
                        const uint8_t* __restrict__ state, uint32_t* __restrict__ mask) {
    int i = blockIdx.x * blockDim.x + threadIdx.x;
    int stride = gridDim.x * blockDim.x;
    for (int e = i; e < EE; e += stride) atomicOr(&mask[dst[e]], 1u << state[src[e]]);
}
__global__ void fb_update(uint8_t* __restrict__ state, uint32_t* __restrict__ mask,
                          const uint8_t* __restrict__ nextT) {
    int i = blockIdx.x * blockDim.x + threadIdx.x;
    if (i < NN) {
        uint32_t m = mask[i];
        state[i] = nextT[(m << 3) + state[i]];
        mask[i] = 0u;
    }
}

extern "C" void kernel_launch(void* const* d_in, const int* in_sizes, int n_in,
                              void* d_out, int out_size, void* d_ws, size_t ws_size,
                              hipStream_t stream) {
    const float* s0  = (const float*)d_in[0];
    const int*   ei  = (const int*)d_in[1];   // [2,E]: row0=src, row1=dst
    const float* T   = (const float*)d_in[2];
    float*       out = (float*)d_out;
    const int* src = ei;
    const int* dst = ei + EE;

    uint8_t* basep = (uint8_t*)d_ws;
    size_t off = 0;
    auto alloc = [&](size_t sz) -> void* {
        void* p = basep + off;
        off += (sz + 255) & ~(size_t)255;
        return p;
    };
    uint32_t* csr         = (uint32_t*)alloc(sizeof(uint32_t) * EE);
    uint32_t* hist        = (uint32_t*)alloc(sizeof(uint32_t) * (size_t)NCHUNK * NBKT);
    uint32_t* total       = (uint32_t*)alloc(sizeof(uint32_t) * NBKT);
    uint32_t* bucket_base = (uint32_t*)alloc(sizeof(uint32_t) * (NBKT + 1));
    uint8_t*  nextT       = (uint8_t*)alloc(NCHARS);
    uint8_t*  stateA      = (uint8_t*)alloc(NN);
    uint8_t*  stateB      = (uint8_t*)alloc(NN);
    bool have_ws = (off <= ws_size);

    const int tb = 256;
    if (have_ws) {
        decode_kernel<<<NB_NODE, tb, 0, stream>>>(s0, T, stateA, nextT);
        p1_hist<<<NCHUNK, tb, 0, stream>>>(dst, hist);
        p2a_scan<<<NBKT, tb, 0, stream>>>(hist, total);
        p2b_scan<<<1, 512, 0, stream>>>(total, bucket_base);
        p3_partition<<<NCHUNK, tb, 0, stream>>>(src, dst, hist, bucket_base, csr);
        p4_bin<<<NBKT, 512, 0, stream>>>(csr, bucket_base);

        uint8_t* cur = stateA;
        uint8_t* nxt = stateB;
        for (int it = 0; it < ITERS; ++it) {
            iter_kernel<<<NBKT, 512, 0, stream>>>(csr, bucket_base, cur, nxt, nextT);
            uint8_t* tmp = cur; cur = nxt; nxt = tmp;
        }
        output_kernel<<<NB_NODE, tb, 0, stream>>>(cur, out);
    } else {
        uint32_t* mask = (uint32_t*)d_ws;           // < 1 MB path
        uint8_t*  nT   = (uint8_t*)d_ws + 400128;
        uint8_t*  st   = (uint8_t*)d_ws + 402432;
        decode_kernel<<<NB_NODE, tb, 0, stream>>>(s0, T, st, nT);
        fb_init<<<NB_NODE, tb, 0, stream>>>(mask);
        for (int it = 0; it < ITERS; ++it) {
            fb_edge<<<2048, tb, 0, stream>>>(src, dst, st, mask);
            fb_update<<<NB_NODE, tb, 0, stream>>>(st, mask, nT);
        }
        output_kernel<<<NB_NODE, tb, 0, stream>>>(st, out);
    }
}